// Round 2
// baseline (151.273 us; speedup 1.0000x reference)
//
#include <hip/hip_runtime.h>
#include <hip/hip_bf16.h>

#define B_DIM 4096
#define D_DIM 768
#define BM 128
#define BN 128
#define BK 64
#define NT (B_DIM / BM)   // 32 tiles per dim

typedef __bf16 bf16_t;
typedef bf16_t bf16x8 __attribute__((ext_vector_type(8)));
typedef float f32x4 __attribute__((ext_vector_type(4)));

static __device__ __forceinline__ ushort f2bf(float v) {
    __hip_bfloat16 h = __float2bfloat16(v);
    return *reinterpret_cast<const ushort*>(&h);
}

// ---------------- Kernel 1: fp32 -> bf16 + row sum-of-squares ----------------
// Wave-per-row: 64 lanes x 3 float4 = 768 elems. No LDS, no __syncthreads.
__global__ __launch_bounds__(256) void prep_kernel(
    const float* __restrict__ E, ushort* __restrict__ Ebf, float* __restrict__ sq)
{
    const int lane = threadIdx.x & 63;
    const int row  = blockIdx.x * 4 + (threadIdx.x >> 6);
    const float4* er = reinterpret_cast<const float4*>(E + (size_t)row * D_DIM);
    ushort4* br = reinterpret_cast<ushort4*>(Ebf + (size_t)row * D_DIM);
    float s = 0.f;
    #pragma unroll
    for (int k = 0; k < 3; ++k) {
        float4 v = er[lane + 64 * k];
        s += v.x * v.x + v.y * v.y + v.z * v.z + v.w * v.w;
        ushort4 o;
        o.x = f2bf(v.x); o.y = f2bf(v.y); o.z = f2bf(v.z); o.w = f2bf(v.w);
        br[lane + 64 * k] = o;
    }
    #pragma unroll
    for (int off = 32; off > 0; off >>= 1) s += __shfl_down(s, off);
    if (lane == 0) sq[row] = s;
}

// ---------------- Kernel 2: fused gram GEMM + loss epilogue ----------------
// Triangular grid: one block per unordered tile pair (I <= J), 528 blocks.
// Gram tile computed ONCE; off-diagonal blocks apply it to both art[I,J]
// (direct) and art[J,I] (mirror, float4 reads down columns of the acc
// layout -> lanes l and l+16 share a 64B line: fully-used transactions).
// GEMM structure identical to the round-1 verified kernel (m97-style):
// 128x128 tile, BK=64, 4 waves 2x2, global_load_lds w=16 with
// inverse-swizzled source + swizzled ds_read (rule #21).
__global__ __launch_bounds__(256) void gram_loss_kernel(
    const ushort* __restrict__ Ebf, const float* __restrict__ sq,
    const float* __restrict__ art, float* __restrict__ out)
{
    __shared__ ushort Als[BM][BK];   // 16 KiB
    __shared__ ushort Bls[BN][BK];   // 16 KiB
    __shared__ float red[4];

    const int tid  = threadIdx.x;
    const int lane = tid & 63;
    const int wave = tid >> 6;
    const int wr = wave >> 1;
    const int wc = wave & 1;

    // decode blockIdx -> (I, J), I <= J, enumerating (I,I)..(I,NT-1)
    int b = blockIdx.x, I = 0, rem = NT;
    while (b >= rem) { b -= rem; ++I; --rem; }
    const int J = I + b;
    const int row0 = I * BM;
    const int col0 = J * BN;

    f32x4 acc[4][4] = {};

    const int srow  = tid >> 3;        // 0..31
    const int scol8 = (tid & 7) * 8;   // linear LDS dest col

    for (int kk = 0; kk < D_DIM; kk += BK) {
        #pragma unroll
        for (int i = 0; i < 4; ++i) {
            const int r = i * 32 + srow;
            const int colg = scol8 ^ ((r & 7) << 3);   // inverse-swizzled source
            const ushort* gA = Ebf + (size_t)(row0 + r) * D_DIM + kk + colg;
            __builtin_amdgcn_global_load_lds(
                (const __attribute__((address_space(1))) void*)gA,
                (__attribute__((address_space(3))) void*)(&Als[r][scol8]),
                16, 0, 0);
            const ushort* gB = Ebf + (size_t)(col0 + r) * D_DIM + kk + colg;
            __builtin_amdgcn_global_load_lds(
                (const __attribute__((address_space(1))) void*)gB,
                (__attribute__((address_space(3))) void*)(&Bls[r][scol8]),
                16, 0, 0);
        }
        __syncthreads();

        #pragma unroll
        for (int k2 = 0; k2 < BK; k2 += 32) {
            bf16x8 af[4], bfr[4];
            #pragma unroll
            for (int m = 0; m < 4; ++m) {
                const int r = wr * 64 + m * 16 + (lane & 15);
                const int c = (k2 + (lane >> 4) * 8) ^ ((r & 7) << 3);
                af[m] = *reinterpret_cast<const bf16x8*>(&Als[r][c]);
            }
            #pragma unroll
            for (int n = 0; n < 4; ++n) {
                const int r = wc * 64 + n * 16 + (lane & 15);
                const int c = (k2 + (lane >> 4) * 8) ^ ((r & 7) << 3);
                bfr[n] = *reinterpret_cast<const bf16x8*>(&Bls[r][c]);
            }
            #pragma unroll
            for (int m = 0; m < 4; ++m)
                #pragma unroll
                for (int n = 0; n < 4; ++n)
                    acc[m][n] = __builtin_amdgcn_mfma_f32_16x16x32_bf16(
                        af[m], bfr[n], acc[m][n], 0, 0, 0);
        }
        __syncthreads();
    }

    // Epilogue. C/D layout (HW-verified): col = lane&15, row = (lane>>4)*4 + j.
    float lsum = 0.f;
    const int lr = (lane >> 4) * 4;
    const int lc = lane & 15;
    const int rbase = row0 + wr * 64;
    const int cbase = col0 + wc * 64;

    if (I != J) {
        #pragma unroll
        for (int m = 0; m < 4; ++m) {
            const int gi0 = rbase + m * 16 + lr;
            #pragma unroll
            for (int n = 0; n < 4; ++n) {
                const int gj = cbase + n * 16 + lc;
                const float sqj = sq[gj];
                // mirror tile art[J,I]: one aligned float4 per (m,n)
                const float4 am = *reinterpret_cast<const float4*>(
                    &art[(size_t)gj * B_DIM + gi0]);
                const float amv[4] = { am.x, am.y, am.z, am.w };
                #pragma unroll
                for (int j = 0; j < 4; ++j) {
                    const int gi = gi0 + j;
                    const float d2 = sq[gi] + sqj - 2.0f * acc[m][n][j];
                    const float t1 = d2 - art[(size_t)gi * B_DIM + gj];
                    const float t2 = d2 - amv[j];
                    lsum += t1 * t1 + t2 * t2;
                }
            }
        }
    } else {
        #pragma unroll
        for (int m = 0; m < 4; ++m) {
            const int gi0 = rbase + m * 16 + lr;
            #pragma unroll
            for (int n = 0; n < 4; ++n) {
                const int gj = cbase + n * 16 + lc;
                const float sqj = sq[gj];
                #pragma unroll
                for (int j = 0; j < 4; ++j) {
                    const int gi = gi0 + j;
                    const float d2 = sq[gi] + sqj - 2.0f * acc[m][n][j];
                    const float t = d2 - art[(size_t)gi * B_DIM + gj];
                    if (gi != gj) lsum += t * t;
                }
            }
        }
    }

    #pragma unroll
    for (int off = 32; off > 0; off >>= 1) lsum += __shfl_down(lsum, off);
    if (lane == 0) red[wave] = lsum;
    __syncthreads();
    if (tid == 0) {
        const float inv_pairs = 1.0f / ((float)B_DIM * (float)(B_DIM - 1));
        atomicAdd(out, (red[0] + red[1] + red[2] + red[3]) * inv_pairs);
    }
}

// ---------------- launch ----------------
extern "C" void kernel_launch(void* const* d_in, const int* in_sizes, int n_in,
                              void* d_out, int out_size, void* d_ws, size_t ws_size,
                              hipStream_t stream) {
    const float* E   = (const float*)d_in[0];   // [4096, 768] fp32
    const float* art = (const float*)d_in[1];   // [4096, 4096] fp32
    float* out = (float*)d_out;                 // scalar fp32

    ushort* Ebf = (ushort*)d_ws;
    float*  sq  = (float*)((char*)d_ws + (size_t)B_DIM * D_DIM * 2);

    hipMemsetAsync(d_out, 0, sizeof(float), stream);
    prep_kernel<<<B_DIM / 4, 256, 0, stream>>>(E, Ebf, sq);
    gram_loss_kernel<<<(NT * (NT + 1)) / 2, 256, 0, stream>>>(Ebf, sq, art, out);
}

// Round 3
// 129.412 us; speedup vs baseline: 1.1689x; 1.1689x over previous
//
#include <hip/hip_runtime.h>
#include <hip/hip_bf16.h>

#define B_DIM 4096
#define D_DIM 768
#define BM 128
#define BN 128
#define BK 64
#define NT (B_DIM / BM)   // 32 tiles per dim

typedef __bf16 bf16_t;
typedef bf16_t bf16x8 __attribute__((ext_vector_type(8)));
typedef float f32x4 __attribute__((ext_vector_type(4)));

static __device__ __forceinline__ ushort f2bf(float v) {
    __hip_bfloat16 h = __float2bfloat16(v);
    return *reinterpret_cast<const ushort*>(&h);
}

// ---------------- Kernel 1: fp32 -> bf16 + row sum-of-squares ----------------
// Wave-per-row: 64 lanes x 3 float4 = 768 elems. No LDS, no __syncthreads.
__global__ __launch_bounds__(256) void prep_kernel(
    const float* __restrict__ E, ushort* __restrict__ Ebf, float* __restrict__ sq)
{
    const int lane = threadIdx.x & 63;
    const int row  = blockIdx.x * 4 + (threadIdx.x >> 6);
    const float4* er = reinterpret_cast<const float4*>(E + (size_t)row * D_DIM);
    ushort4* br = reinterpret_cast<ushort4*>(Ebf + (size_t)row * D_DIM);
    float s = 0.f;
    #pragma unroll
    for (int k = 0; k < 3; ++k) {
        float4 v = er[lane + 64 * k];
        s += v.x * v.x + v.y * v.y + v.z * v.z + v.w * v.w;
        ushort4 o;
        o.x = f2bf(v.x); o.y = f2bf(v.y); o.z = f2bf(v.z); o.w = f2bf(v.w);
        br[lane + 64 * k] = o;
    }
    #pragma unroll
    for (int off = 32; off > 0; off >>= 1) s += __shfl_down(s, off);
    if (lane == 0) sq[row] = s;
}

// ---------------- Kernel 2: fused gram GEMM + loss epilogue ----------------
// Full 1024-block grid (4 blocks/CU — round-1 verified occupancy), m97-style
// 128x128 tile, BK=64, 4 waves 2x2, global_load_lds w=16 with
// inverse-swizzled source + swizzled ds_read (rule #21).
//
// Epilogue reads the TRANSPOSED art tile: sum_{i!=j}(d2_ij - art_ji)^2 equals
// the reference sum exactly (relabel i<->j; d2 is symmetric). This makes the
// per-thread art access an aligned float4 (art[gj][gi0..gi0+3]) instead of a
// 4-row scalar column: 16 float4 loads/thread vs 64 scalar loads.
//
// __launch_bounds__(256, 4): pin VGPR <= 128 so the epilogue's load batching
// cannot push us into the 8-wave occupancy class (round-2 failure mode).
__global__ __launch_bounds__(256, 4) void gram_loss_kernel(
    const ushort* __restrict__ Ebf, const float* __restrict__ sq,
    const float* __restrict__ art, float* __restrict__ out)
{
    __shared__ ushort Als[BM][BK];   // 16 KiB
    __shared__ ushort Bls[BN][BK];   // 16 KiB
    __shared__ float red[4];

    const int tid  = threadIdx.x;
    const int lane = tid & 63;
    const int wave = tid >> 6;
    const int wr = wave >> 1;
    const int wc = wave & 1;

    // T1: bijective XCD swizzle (1024 blocks % 8 XCDs == 0, chunk = 128).
    // Each XCD gets 128 consecutive work-ids = 4 full A row-panels -> L2 reuse.
    const int swz = (blockIdx.x & 7) * 128 + (blockIdx.x >> 3);
    const int tileR = swz >> 5;
    const int tileC = swz & 31;
    const int row0 = tileR * BM;
    const int col0 = tileC * BN;

    f32x4 acc[4][4] = {};

    const int srow  = tid >> 3;        // 0..31
    const int scol8 = (tid & 7) * 8;   // linear LDS dest col

    for (int kk = 0; kk < D_DIM; kk += BK) {
        #pragma unroll
        for (int i = 0; i < 4; ++i) {
            const int r = i * 32 + srow;
            const int colg = scol8 ^ ((r & 7) << 3);   // inverse-swizzled source
            const ushort* gA = Ebf + (size_t)(row0 + r) * D_DIM + kk + colg;
            __builtin_amdgcn_global_load_lds(
                (const __attribute__((address_space(1))) void*)gA,
                (__attribute__((address_space(3))) void*)(&Als[r][scol8]),
                16, 0, 0);
            const ushort* gB = Ebf + (size_t)(col0 + r) * D_DIM + kk + colg;
            __builtin_amdgcn_global_load_lds(
                (const __attribute__((address_space(1))) void*)gB,
                (__attribute__((address_space(3))) void*)(&Bls[r][scol8]),
                16, 0, 0);
        }
        __syncthreads();

        #pragma unroll
        for (int k2 = 0; k2 < BK; k2 += 32) {
            bf16x8 af[4], bfr[4];
            #pragma unroll
            for (int m = 0; m < 4; ++m) {
                const int r = wr * 64 + m * 16 + (lane & 15);
                const int c = (k2 + (lane >> 4) * 8) ^ ((r & 7) << 3);
                af[m] = *reinterpret_cast<const bf16x8*>(&Als[r][c]);
            }
            #pragma unroll
            for (int n = 0; n < 4; ++n) {
                const int r = wc * 64 + n * 16 + (lane & 15);
                const int c = (k2 + (lane >> 4) * 8) ^ ((r & 7) << 3);
                bfr[n] = *reinterpret_cast<const bf16x8*>(&Bls[r][c]);
            }
            #pragma unroll
            for (int m = 0; m < 4; ++m)
                #pragma unroll
                for (int n = 0; n < 4; ++n)
                    acc[m][n] = __builtin_amdgcn_mfma_f32_16x16x32_bf16(
                        af[m], bfr[n], acc[m][n], 0, 0, 0);
        }
        __syncthreads();
    }

    // Epilogue. C/D layout (HW-verified): col = lane&15, row = (lane>>4)*4 + j.
    // Transposed-art read: per (m,n) one float4 = art[gj][gi0 .. gi0+3].
    float lsum = 0.f;
    const int lr = (lane >> 4) * 4;
    const int lc = lane & 15;
    const int rbase = row0 + wr * 64;
    const int cbase = col0 + wc * 64;

    if (tileR != tileC) {
        #pragma unroll
        for (int m = 0; m < 4; ++m) {
            const int gi0 = rbase + m * 16 + lr;
            float sqi[4];
            #pragma unroll
            for (int j = 0; j < 4; ++j) sqi[j] = sq[gi0 + j];
            #pragma unroll
            for (int n = 0; n < 4; ++n) {
                const int gj = cbase + n * 16 + lc;
                const float sqj = sq[gj];
                const float4 am = *reinterpret_cast<const float4*>(
                    &art[(size_t)gj * B_DIM + gi0]);
                const float amv[4] = { am.x, am.y, am.z, am.w };
                #pragma unroll
                for (int j = 0; j < 4; ++j) {
                    const float d2 = sqi[j] + sqj - 2.0f * acc[m][n][j];
                    const float t = d2 - amv[j];
                    lsum += t * t;
                }
            }
        }
    } else {
        #pragma unroll
        for (int m = 0; m < 4; ++m) {
            const int gi0 = rbase + m * 16 + lr;
            float sqi[4];
            #pragma unroll
            for (int j = 0; j < 4; ++j) sqi[j] = sq[gi0 + j];
            #pragma unroll
            for (int n = 0; n < 4; ++n) {
                const int gj = cbase + n * 16 + lc;
                const float sqj = sq[gj];
                const float4 am = *reinterpret_cast<const float4*>(
                    &art[(size_t)gj * B_DIM + gi0]);
                const float amv[4] = { am.x, am.y, am.z, am.w };
                #pragma unroll
                for (int j = 0; j < 4; ++j) {
                    const int gi = gi0 + j;
                    const float d2 = sqi[j] + sqj - 2.0f * acc[m][n][j];
                    const float t = d2 - amv[j];
                    if (gi != gj) lsum += t * t;
                }
            }
        }
    }

    #pragma unroll
    for (int off = 32; off > 0; off >>= 1) lsum += __shfl_down(lsum, off);
    if (lane == 0) red[wave] = lsum;
    __syncthreads();
    if (tid == 0) {
        const float inv_pairs = 1.0f / ((float)B_DIM * (float)(B_DIM - 1));
        atomicAdd(out, (red[0] + red[1] + red[2] + red[3]) * inv_pairs);
    }
}

// ---------------- launch ----------------
extern "C" void kernel_launch(void* const* d_in, const int* in_sizes, int n_in,
                              void* d_out, int out_size, void* d_ws, size_t ws_size,
                              hipStream_t stream) {
    const float* E   = (const float*)d_in[0];   // [4096, 768] fp32
    const float* art = (const float*)d_in[1];   // [4096, 4096] fp32
    float* out = (float*)d_out;                 // scalar fp32

    ushort* Ebf = (ushort*)d_ws;
    float*  sq  = (float*)((char*)d_ws + (size_t)B_DIM * D_DIM * 2);

    hipMemsetAsync(d_out, 0, sizeof(float), stream);
    prep_kernel<<<B_DIM / 4, 256, 0, stream>>>(E, Ebf, sq);
    gram_loss_kernel<<<NT * NT, 256, 0, stream>>>(Ebf, sq, art, out);
}

// Round 4
// 129.412 us; speedup vs baseline: 1.1689x; 1.0000x over previous
//
#include <hip/hip_runtime.h>
#include <hip/hip_bf16.h>

#define B_DIM 4096
#define D_DIM 768
#define BM 256            // tile is BM x BM
#define BK 64
#define NSTEP (D_DIM / BK)   // 12
#define NTI (B_DIM / BM)     // 16 tiles per dim -> 256 blocks

typedef __bf16 bf16_t;
typedef bf16_t bf16x8 __attribute__((ext_vector_type(8)));
typedef float f32x4 __attribute__((ext_vector_type(4)));

static __device__ __forceinline__ ushort f2bf(float v) {
    __hip_bfloat16 h = __float2bfloat16(v);
    return *reinterpret_cast<const ushort*>(&h);
}

// ---------------- Kernel 1: fp32 -> bf16 + row sum-of-squares ----------------
__global__ __launch_bounds__(256) void prep_kernel(
    const float* __restrict__ E, ushort* __restrict__ Ebf, float* __restrict__ sq)
{
    const int lane = threadIdx.x & 63;
    const int row  = blockIdx.x * 4 + (threadIdx.x >> 6);
    const float4* er = reinterpret_cast<const float4*>(E + (size_t)row * D_DIM);
    ushort4* br = reinterpret_cast<ushort4*>(Ebf + (size_t)row * D_DIM);
    float s = 0.f;
    #pragma unroll
    for (int k = 0; k < 3; ++k) {
        float4 v = er[lane + 64 * k];
        s += v.x * v.x + v.y * v.y + v.z * v.z + v.w * v.w;
        ushort4 o;
        o.x = f2bf(v.x); o.y = f2bf(v.y); o.z = f2bf(v.z); o.w = f2bf(v.w);
        br[lane + 64 * k] = o;
    }
    #pragma unroll
    for (int off = 32; off > 0; off >>= 1) s += __shfl_down(s, off);
    if (lane == 0) sq[row] = s;
}

// ---------------- gram GEMM helpers ----------------
// Staging chunk P (1..4) of one K-step (16 KB each, 2 gload_lds/thread):
//   C1: A rows {0-63, 128-191}     (quadrant QM=0 rows for both wr halves)
//   C2: A rows {64-127, 192-255}   (QM=1)
//   C3: B rows {0-31,64-95,128-159,192-223}   (QN=0 col-stripes)
//   C4: B rows {32-63,96-127,160-191,224-255} (QN=1)
// LDS dest linear (wave-contiguous, required by global_load_lds); global
// source col pre-swizzled chunk^(r&7) (rule #21 pair with the swizzled read).
template<int P>
__device__ __forceinline__ void issue_chunk(
    const ushort* __restrict__ Ebf, ushort* lbase, int panel_row0, int kkn, int tid)
{
    #pragma unroll
    for (int q = 0; q < 2; ++q) {
        const int idx = q * 512 + tid;
        const int rl  = idx >> 3;        // 0..127
        const int c16 = idx & 7;         // 16B chunk within 64-col row
        int r;
        if      (P == 1) r = rl + (rl & 64);
        else if (P == 2) r = 64 + rl + (rl & 64);
        else if (P == 3) r = ((rl >> 5) << 6) + (rl & 31);
        else             r = ((rl >> 5) << 6) + 32 + (rl & 31);
        const int cg = (c16 ^ (r & 7)) << 3;   // inverse-swizzled source col (elems)
        const ushort* gsrc = Ebf + (size_t)(panel_row0 + r) * D_DIM + kkn + cg;
        ushort* ldst = lbase + r * 64 + c16 * 8;
        __builtin_amdgcn_global_load_lds(
            (const __attribute__((address_space(1))) void*)gsrc,
            (__attribute__((address_space(3))) void*)ldst, 16, 0, 0);
    }
}

// One quadrant phase: 12 swizzled ds_read_b128 + 16 MFMA (setprio-wrapped, T5).
template<int QM, int QN>
__device__ __forceinline__ void phase_mfma(
    const ushort* Acur, const ushort* Bcur, f32x4 (&acc)[8][4],
    int wr, int wc, int lane)
{
    bf16x8 af[4][2], bv[2][2];
    const int l15 = lane & 15;
    const int kq  = (lane >> 4) * 8;
    #pragma unroll
    for (int mm = 0; mm < 4; ++mm)
        #pragma unroll
        for (int k2 = 0; k2 < 2; ++k2) {
            const int ra = wr * 128 + QM * 64 + mm * 16 + l15;
            const int c  = (k2 * 32 + kq) ^ ((ra & 7) << 3);
            af[mm][k2] = *reinterpret_cast<const bf16x8*>(Acur + ra * 64 + c);
        }
    #pragma unroll
    for (int nn = 0; nn < 2; ++nn)
        #pragma unroll
        for (int k2 = 0; k2 < 2; ++k2) {
            const int rb = wc * 64 + QN * 32 + nn * 16 + l15;
            const int c  = (k2 * 32 + kq) ^ ((rb & 7) << 3);
            bv[nn][k2] = *reinterpret_cast<const bf16x8*>(Bcur + rb * 64 + c);
        }
    __builtin_amdgcn_s_setprio(1);
    #pragma unroll
    for (int mm = 0; mm < 4; ++mm)
        #pragma unroll
        for (int nn = 0; nn < 2; ++nn)
            #pragma unroll
            for (int k2 = 0; k2 < 2; ++k2)
                acc[QM * 4 + mm][QN * 2 + nn] = __builtin_amdgcn_mfma_f32_16x16x32_bf16(
                    af[mm][k2], bv[nn][k2], acc[QM * 4 + mm][QN * 2 + nn], 0, 0, 0);
    __builtin_amdgcn_s_setprio(0);
}

// ---------------- Kernel 2: 256^2-tile counted-vmcnt pipelined GEMM + loss ----
// 8 waves (2x4), wave tile 128x64, BK=64, 12 K-steps, LDS double-buffered
// (2 x 32KB per operand = 128 KB dynamic). Per K-step: 4 quadrant phases.
// Counted waits (never vmcnt(0) in the loop):
//   boundary A: vmcnt(2)  -- C1..C3 of this step landed, C4 may fly
//   boundary B: vmcnt(4)  -- C4 landed, C1',C2' (next step) may fly
// Raw s_barrier (NOT __syncthreads) so the compiler doesn't drain the queue.
__global__ __launch_bounds__(512, 2) void gram_loss_kernel(
    const ushort* __restrict__ Ebf, const float* __restrict__ sq,
    const float* __restrict__ art, float* __restrict__ out)
{
    extern __shared__ char smem[];
    ushort* Ab = (ushort*)smem;              // 2 x [256][64] ushort = 64 KB
    ushort* Bb = (ushort*)(smem + 65536);    // 2 x [256][64] ushort = 64 KB
    float*  red = (float*)(smem + 131072);   // 8 floats

    const int tid  = threadIdx.x;
    const int lane = tid & 63;
    const int wave = tid >> 6;   // 0..7
    const int wr = wave >> 2;    // 0..1
    const int wc = wave & 3;     // 0..3

    // T1: bijective XCD swizzle (256 blocks % 8 == 0, chunk 32 = 2 row-panels/XCD)
    const int swz = (blockIdx.x & 7) * 32 + (blockIdx.x >> 3);
    const int tileR = swz >> 4;
    const int tileC = swz & 15;
    const int row0 = tileR * BM;
    const int col0 = tileC * BM;

    f32x4 acc[8][4] = {};

    // prologue: stage step 0 into buffer 0 (issue order C1,C2,C3,C4)
    issue_chunk<1>(Ebf, Ab, row0, 0, tid);
    issue_chunk<2>(Ebf, Ab, row0, 0, tid);
    issue_chunk<3>(Ebf, Bb, col0, 0, tid);
    issue_chunk<4>(Ebf, Bb, col0, 0, tid);

    #pragma unroll 2
    for (int s = 0; s < NSTEP; ++s) {
        const int b = s & 1;
        const int kkn = ((s + 1) % NSTEP) * BK;   // wrapped tail: harmless reload
        const ushort* Acur = Ab + b * 16384;
        const ushort* Bcur = Bb + b * 16384;
        ushort* Anxt = Ab + (b ^ 1) * 16384;
        ushort* Bnxt = Bb + (b ^ 1) * 16384;

        // ---- boundary A: C1..C3 landed everywhere; prior-step reads all done
        asm volatile("s_waitcnt vmcnt(2)" ::: "memory");
        __builtin_amdgcn_s_barrier();
        __builtin_amdgcn_sched_barrier(0);

        issue_chunk<1>(Ebf, Anxt, row0, kkn, tid);      // C1' -> buf^1 (safe: its readers done)
        phase_mfma<0, 0>(Acur, Bcur, acc, wr, wc, lane);
        issue_chunk<2>(Ebf, Anxt, row0, kkn, tid);      // C2'
        phase_mfma<1, 0>(Acur, Bcur, acc, wr, wc, lane);

        // ---- boundary B: C4 landed everywhere (C1',C2' may fly)
        asm volatile("s_waitcnt vmcnt(4)" ::: "memory");
        __builtin_amdgcn_s_barrier();
        __builtin_amdgcn_sched_barrier(0);

        issue_chunk<3>(Ebf, Bnxt, col0, kkn, tid);      // C3'
        phase_mfma<0, 1>(Acur, Bcur, acc, wr, wc, lane);
        issue_chunk<4>(Ebf, Bnxt, col0, kkn, tid);      // C4'
        phase_mfma<1, 1>(Acur, Bcur, acc, wr, wc, lane);
    }

    // Epilogue. C/D layout (HW-verified): col = lane&15, row = (lane>>4)*4 + j.
    // Transposed-art trick: sum_{i!=j}(d2_ij - art_ji)^2 == reference sum
    // (relabel, d2 symmetric) -> per (m,n) one aligned float4 art[gj][gi0..+3].
    float lsum = 0.f;
    const int lr = (lane >> 4) * 4;
    const int lc = lane & 15;
    const int rbase = row0 + wr * 128;
    const int cbase = col0 + wc * 64;

    if (tileR != tileC) {
        #pragma unroll
        for (int m = 0; m < 8; ++m) {
            const int gi0 = rbase + m * 16 + lr;
            const float4 sqv = *reinterpret_cast<const float4*>(sq + gi0);
            const float sqi[4] = { sqv.x, sqv.y, sqv.z, sqv.w };
            #pragma unroll
            for (int n = 0; n < 4; ++n) {
                const int gj = cbase + n * 16 + lc;
                const float sqj = sq[gj];
                const float4 am = *reinterpret_cast<const float4*>(
                    &art[(size_t)gj * B_DIM + gi0]);
                const float amv[4] = { am.x, am.y, am.z, am.w };
                #pragma unroll
                for (int j = 0; j < 4; ++j) {
                    const float d2 = sqi[j] + sqj - 2.0f * acc[m][n][j];
                    const float t = d2 - amv[j];
                    lsum += t * t;
                }
            }
        }
    } else {
        #pragma unroll
        for (int m = 0; m < 8; ++m) {
            const int gi0 = rbase + m * 16 + lr;
            const float4 sqv = *reinterpret_cast<const float4*>(sq + gi0);
            const float sqi[4] = { sqv.x, sqv.y, sqv.z, sqv.w };
            #pragma unroll
            for (int n = 0; n < 4; ++n) {
                const int gj = cbase + n * 16 + lc;
                const float sqj = sq[gj];
                const float4 am = *reinterpret_cast<const float4*>(
                    &art[(size_t)gj * B_DIM + gi0]);
                const float amv[4] = { am.x, am.y, am.z, am.w };
                #pragma unroll
                for (int j = 0; j < 4; ++j) {
                    const int gi = gi0 + j;
                    const float d2 = sqi[j] + sqj - 2.0f * acc[m][n][j];
                    const float t = d2 - amv[j];
                    if (gi != gj) lsum += t * t;
                }
            }
        }
    }

    #pragma unroll
    for (int off = 32; off > 0; off >>= 1) lsum += __shfl_down(lsum, off);
    if (lane == 0) red[wave] = lsum;
    __syncthreads();
    if (tid == 0) {
        float tot = 0.f;
        #pragma unroll
        for (int w = 0; w < 8; ++w) tot += red[w];
        const float inv_pairs = 1.0f / ((float)B_DIM * (float)(B_DIM - 1));
        atomicAdd(out, tot * inv_pairs);
    }
}

// ---------------- launch ----------------
extern "C" void kernel_launch(void* const* d_in, const int* in_sizes, int n_in,
                              void* d_out, int out_size, void* d_ws, size_t ws_size,
                              hipStream_t stream) {
    const float* E   = (const float*)d_in[0];   // [4096, 768] fp32
    const float* art = (const float*)d_in[1];   // [4096, 4096] fp32
    float* out = (float*)d_out;                 // scalar fp32

    ushort* Ebf = (ushort*)d_ws;
    float*  sq  = (float*)((char*)d_ws + (size_t)B_DIM * D_DIM * 2);

    const int lds_bytes = 131072 + 256;
    (void)hipFuncSetAttribute((const void*)gram_loss_kernel,
                              hipFuncAttributeMaxDynamicSharedMemorySize, lds_bytes);

    hipMemsetAsync(d_out, 0, sizeof(float), stream);
    prep_kernel<<<B_DIM / 4, 256, 0, stream>>>(E, Ebf, sq);
    gram_loss_kernel<<<NTI * NTI, 512, lds_bytes, stream>>>(Ebf, sq, art, out);
}

// Round 6
// 128.258 us; speedup vs baseline: 1.1794x; 1.0090x over previous
//
#include <hip/hip_runtime.h>
#include <hip/hip_bf16.h>

#define B_DIM 4096
#define D_DIM 768
#define BM 256            // tile is BM x BM
#define BK 64
#define NSTEP (D_DIM / BK)   // 12
#define NTI (B_DIM / BM)     // 16 tiles per dim -> 256 blocks

typedef __bf16 bf16_t;
typedef bf16_t bf16x8 __attribute__((ext_vector_type(8)));
typedef float f32x4 __attribute__((ext_vector_type(4)));

static __device__ __forceinline__ ushort f2bf(float v) {
    __hip_bfloat16 h = __float2bfloat16(v);
    return *reinterpret_cast<const ushort*>(&h);
}

// ---------------- Kernel 1: fp32 -> bf16 + row sum-of-squares ----------------
__global__ __launch_bounds__(256) void prep_kernel(
    const float* __restrict__ E, ushort* __restrict__ Ebf, float* __restrict__ sq)
{
    const int lane = threadIdx.x & 63;
    const int row  = blockIdx.x * 4 + (threadIdx.x >> 6);
    const float4* er = reinterpret_cast<const float4*>(E + (size_t)row * D_DIM);
    ushort4* br = reinterpret_cast<ushort4*>(Ebf + (size_t)row * D_DIM);
    float s = 0.f;
    #pragma unroll
    for (int k = 0; k < 3; ++k) {
        float4 v = er[lane + 64 * k];
        s += v.x * v.x + v.y * v.y + v.z * v.z + v.w * v.w;
        ushort4 o;
        o.x = f2bf(v.x); o.y = f2bf(v.y); o.z = f2bf(v.z); o.w = f2bf(v.w);
        br[lane + 64 * k] = o;
    }
    #pragma unroll
    for (int off = 32; off > 0; off >>= 1) s += __shfl_down(s, off);
    if (lane == 0) sq[row] = s;
}

// ---------------- staging: one K-step tile (A 32KB + B 32KB), 8 gload_lds ----
// Linear LDS dest (wave-contiguous, required by global_load_lds); global
// source col pre-swizzled c16 ^ (r&7) (rule #21 pair with the swizzled read).
__device__ __forceinline__ void stage_step(
    const ushort* __restrict__ Ebf, ushort* Adst, ushort* Bdst,
    int row0, int col0, int kk, int tid)
{
    #pragma unroll
    for (int q = 0; q < 4; ++q) {
        const int idx = q * 512 + tid;
        const int rl  = idx >> 3;        // 0..255
        const int c16 = idx & 7;         // 16B chunk within 64-col row
        const int cg  = (c16 ^ (rl & 7)) << 3;   // inverse-swizzled source col
        const ushort* gA = Ebf + (size_t)(row0 + rl) * D_DIM + kk + cg;
        __builtin_amdgcn_global_load_lds(
            (const __attribute__((address_space(1))) void*)gA,
            (__attribute__((address_space(3))) void*)(Adst + rl * 64 + c16 * 8),
            16, 0, 0);
        const ushort* gB = Ebf + (size_t)(col0 + rl) * D_DIM + kk + cg;
        __builtin_amdgcn_global_load_lds(
            (const __attribute__((address_space(1))) void*)gB,
            (__attribute__((address_space(3))) void*)(Bdst + rl * 64 + c16 * 8),
            16, 0, 0);
    }
}

// ---------------- compute: one full K-step, B register-blocked -------------
// 8 B-frag reads held in regs (32 VGPRs), A streamed 2 reads per m-group.
// 24 ds_read_b128 + 64 MFMA per wave per step (was 48 reads in round 4).
__device__ __forceinline__ void compute_step(
    const ushort* Acur, const ushort* Bcur, f32x4 (&acc)[8][4],
    int wr, int wc, int lane)
{
    const int l15 = lane & 15;
    const int kq  = (lane >> 4) * 8;
    bf16x8 bv[4][2];
    #pragma unroll
    for (int nn = 0; nn < 4; ++nn)
        #pragma unroll
        for (int k2 = 0; k2 < 2; ++k2) {
            const int rb = wc * 64 + nn * 16 + l15;
            const int c  = (k2 * 32 + kq) ^ ((rb & 7) << 3);
            bv[nn][k2] = *reinterpret_cast<const bf16x8*>(Bcur + rb * 64 + c);
        }
    #pragma unroll
    for (int mm = 0; mm < 8; ++mm) {
        const int ra = wr * 128 + mm * 16 + l15;
        const bf16x8 af0 = *reinterpret_cast<const bf16x8*>(
            Acur + ra * 64 + (kq ^ ((ra & 7) << 3)));
        const bf16x8 af1 = *reinterpret_cast<const bf16x8*>(
            Acur + ra * 64 + ((32 + kq) ^ ((ra & 7) << 3)));
        __builtin_amdgcn_s_setprio(1);
        #pragma unroll
        for (int nn = 0; nn < 4; ++nn) {
            acc[mm][nn] = __builtin_amdgcn_mfma_f32_16x16x32_bf16(
                af0, bv[nn][0], acc[mm][nn], 0, 0, 0);
            acc[mm][nn] = __builtin_amdgcn_mfma_f32_16x16x32_bf16(
                af1, bv[nn][1], acc[mm][nn], 0, 0, 0);
        }
        __builtin_amdgcn_s_setprio(0);
    }
}

// ---------------- Kernel 2: 256^2 tile, 3-buffer 2-deep counted pipeline ----
// 8 waves (2x4), wave tile 128x64, BK=64, 12 K-steps, ONE barrier per step.
// Boundary wait: vmcnt(8) -- next step's 8 loads may fly, never drained to 0.
// Buffer safety: stage of step s targets buf[(s+2)%3]; its readers (step s-1)
// finished before the step-s barrier; stages are issued after it.
__global__ __launch_bounds__(512, 2) void gram_loss_kernel(
    const ushort* __restrict__ Ebf, const float* __restrict__ sq,
    const float* __restrict__ art, float* __restrict__ out)
{
    extern __shared__ char smem[];
    ushort* Ab = (ushort*)smem;              // 3 x [256][64] ushort = 48 KB
    ushort* Bb = (ushort*)(smem + 49152);    // 3 x [256][64] ushort = 48 KB
    float*  red = (float*)(smem + 98304);    // 8 floats

    const int tid  = threadIdx.x;
    const int lane = tid & 63;
    const int wave = tid >> 6;   // 0..7
    const int wr = wave >> 2;    // 0..1
    const int wc = wave & 3;     // 0..3

    // T1: bijective XCD swizzle (256 blocks % 8 == 0, chunk 32)
    const int swz = (blockIdx.x & 7) * 32 + (blockIdx.x >> 3);
    const int tileR = swz >> 4;
    const int tileC = swz & 15;
    const int row0 = tileR * BM;
    const int col0 = tileC * BM;

    f32x4 acc[8][4] = {};

    // prologue: stage steps 0 and 1 (16 loads in flight)
    stage_step(Ebf, Ab, Bb, row0, col0, 0, tid);
    stage_step(Ebf, Ab + 8192, Bb + 8192, row0, col0, BK, tid);

    #pragma unroll 3
    for (int st = 0; st < NSTEP; ++st) {
        const int cur = st % 3;
        const int pre = (st + 2) % 3;
        const int kpre = ((st + 2) % NSTEP) * BK;   // wrapped tail: harmless reload

        // boundary: this step's tile landed (own 8 oldest), next step's may fly
        asm volatile("s_waitcnt vmcnt(8)" ::: "memory");
        __builtin_amdgcn_s_barrier();
        __builtin_amdgcn_sched_barrier(0);

        stage_step(Ebf, Ab + pre * 8192, Bb + pre * 8192, row0, col0, kpre, tid);
        compute_step(Ab + cur * 8192, Bb + cur * 8192, acc, wr, wc, lane);
    }

    // Epilogue. C/D layout (HW-verified): col = lane&15, row = (lane>>4)*4 + j.
    // Transposed-art trick: sum_{i!=j}(d2_ij - art_ji)^2 == reference sum
    // (relabel, d2 symmetric) -> per (m,n) one aligned float4 art[gj][gi0..+3].
    float lsum = 0.f;
    const int lr = (lane >> 4) * 4;
    const int lc = lane & 15;
    const int rbase = row0 + wr * 128;
    const int cbase = col0 + wc * 64;

    if (tileR != tileC) {
        #pragma unroll
        for (int m = 0; m < 8; ++m) {
            const int gi0 = rbase + m * 16 + lr;
            const float4 sqv = *reinterpret_cast<const float4*>(sq + gi0);
            const float sqi[4] = { sqv.x, sqv.y, sqv.z, sqv.w };
            #pragma unroll
            for (int n = 0; n < 4; ++n) {
                const int gj = cbase + n * 16 + lc;
                const float sqj = sq[gj];
                const float4 am = *reinterpret_cast<const float4*>(
                    &art[(size_t)gj * B_DIM + gi0]);
                const float amv[4] = { am.x, am.y, am.z, am.w };
                #pragma unroll
                for (int j = 0; j < 4; ++j) {
                    const float d2 = sqi[j] + sqj - 2.0f * acc[m][n][j];
                    const float t = d2 - amv[j];
                    lsum += t * t;
                }
            }
        }
    } else {
        #pragma unroll
        for (int m = 0; m < 8; ++m) {
            const int gi0 = rbase + m * 16 + lr;
            const float4 sqv = *reinterpret_cast<const float4*>(sq + gi0);
            const float sqi[4] = { sqv.x, sqv.y, sqv.z, sqv.w };
            #pragma unroll
            for (int n = 0; n < 4; ++n) {
                const int gj = cbase + n * 16 + lc;
                const float sqj = sq[gj];
                const float4 am = *reinterpret_cast<const float4*>(
                    &art[(size_t)gj * B_DIM + gi0]);
                const float amv[4] = { am.x, am.y, am.z, am.w };
                #pragma unroll
                for (int j = 0; j < 4; ++j) {
                    const int gi = gi0 + j;
                    const float d2 = sqi[j] + sqj - 2.0f * acc[m][n][j];
                    const float t = d2 - amv[j];
                    if (gi != gj) lsum += t * t;
                }
            }
        }
    }

    #pragma unroll
    for (int off = 32; off > 0; off >>= 1) lsum += __shfl_down(lsum, off);
    if (lane == 0) red[wave] = lsum;
    __syncthreads();
    if (tid == 0) {
        float tot = 0.f;
        #pragma unroll
        for (int w = 0; w < 8; ++w) tot += red[w];
        const float inv_pairs = 1.0f / ((float)B_DIM * (float)(B_DIM - 1));
        atomicAdd(out, tot * inv_pairs);
    }
}

// ---------------- launch ----------------
extern "C" void kernel_launch(void* const* d_in, const int* in_sizes, int n_in,
                              void* d_out, int out_size, void* d_ws, size_t ws_size,
                              hipStream_t stream) {
    const float* E   = (const float*)d_in[0];   // [4096, 768] fp32
    const float* art = (const float*)d_in[1];   // [4096, 4096] fp32
    float* out = (float*)d_out;                 // scalar fp32

    ushort* Ebf = (ushort*)d_ws;
    float*  sq  = (float*)((char*)d_ws + (size_t)B_DIM * D_DIM * 2);

    const int lds_bytes = 98304 + 64;
    (void)hipFuncSetAttribute((const void*)gram_loss_kernel,
                              hipFuncAttributeMaxDynamicSharedMemorySize, lds_bytes);

    hipMemsetAsync(d_out, 0, sizeof(float), stream);
    prep_kernel<<<B_DIM / 4, 256, 0, stream>>>(E, Ebf, sq);
    gram_loss_kernel<<<NTI * NTI, 512, lds_bytes, stream>>>(Ebf, sq, art, out);
}